// Round 1
// 568.250 us; speedup vs baseline: 1.0293x; 1.0293x over previous
//
#include <hip/hip_runtime.h>

typedef unsigned short u16;
typedef unsigned int u32;
typedef short s8v __attribute__((ext_vector_type(8)));   // 8 x bf16 bits (4 VGPRs)
typedef float f4v __attribute__((ext_vector_type(4)));   // MFMA accumulator
typedef u32 u32x4 __attribute__((ext_vector_type(4)));

// ---------- helpers ----------
__device__ __forceinline__ u16 f2bf(float f) {
    u32 u = __float_as_uint(f);
    u += 0x7FFFu + ((u >> 16) & 1u);   // round-to-nearest-even
    return (u16)(u >> 16);
}

__device__ __forceinline__ void async_load16(const u16* g, u16* l) {
    // global -> LDS DMA, 16B per lane; LDS dest = wave-uniform base + lane*16
    __builtin_amdgcn_global_load_lds(
        (const __attribute__((address_space(1))) u32*)g,
        (__attribute__((address_space(3))) u32*)l,
        16, 0, 0);
}

// ---------- kernel 0: style (once per b, coalesced mod_w via LDS) ----------
__global__ void style_kernel(const float* __restrict__ norm_feat,  // [8][64]
                             const float* __restrict__ mod_w,      // [256][64]
                             const float* __restrict__ mod_b,      // [256]
                             float* __restrict__ style) {          // [8][256]
    __shared__ float nf[64];
    __shared__ float mw[256][65];
    const int b = blockIdx.x;
    const int tid = threadIdx.x;

    if (tid < 64) nf[tid] = norm_feat[b * 64 + tid];
    #pragma unroll
    for (int i = 0; i < 64; ++i) {
        int idx = i * 256 + tid;
        mw[idx >> 6][idx & 63] = mod_w[idx];
    }
    __syncthreads();

    float s = mod_b[tid];
    #pragma unroll 8
    for (int d = 0; d < 64; ++d) s += nf[d] * mw[tid][d];
    style[b * 256 + tid] = s;
}

// ---------- kernel 1: demod + modulated bf16 weights ----------
// grid (256 co, 8 b), 256 threads (thread = ci)
// NEW Wmod layout (fragment-ordered): [b][t][co>>4][ci>>5][lane=( (ci>>3)&3 )*16 + (co&15)][ci&7]
// so conv's afr load is a single fully-coalesced 16B/lane read per (t, i).
__global__ void modulate_kernel(const float* __restrict__ style,   // [8][256]
                                const float* __restrict__ weight,  // [256][256][9]
                                u16* __restrict__ Wmod) {
    const int co = blockIdx.x;
    const int b  = blockIdx.y;
    const int ci = threadIdx.x;

    __shared__ float red[256];

    const float s = style[b * 256 + ci];

    float w9[9];
    const float* wp = weight + ((size_t)co * 256 + ci) * 9;
    float sq = 0.f;
    #pragma unroll
    for (int t = 0; t < 9; ++t) { w9[t] = wp[t]; sq += w9[t] * w9[t]; }

    red[ci] = sq * s * s;
    __syncthreads();
    for (int off = 128; off > 0; off >>= 1) {
        if (ci < off) red[ci] += red[ci + off];
        __syncthreads();
    }
    const float scale = 1.0f / 48.0f;              // 1/sqrt(256*9)
    const float demod = rsqrtf(scale * scale * red[0] + 1e-8f);
    const float coef  = scale * s * demod;

    // base index for t=0; each t adds 16*8*512 = 65536 u16
    const size_t tile = ((((size_t)b * 9) * 16 + (co >> 4)) * 8 + (ci >> 5)) * 512
                      + (size_t)((ci >> 3) & 3) * 128 + (size_t)(co & 15) * 8 + (ci & 7);
    #pragma unroll
    for (int t = 0; t < 9; ++t) {
        Wmod[tile + (size_t)t * 65536] = f2bf(w9[t] * coef);
    }
}

// ---------- kernel 2: NCHW fp32 -> blocked-NHWC bf16 ----------
// NEW feaT layout: [b][y][cchunk(8)][cg(4)][x(128)][cil(8)] bf16
//   (c = cchunk*32 + cg*8 + cil)
// 1024B units (cg, 64 x) are contiguous -> conv DMA is fully contiguous, and
// linear DMA lands as [cg][x][8] in LDS -> conflict-free ds_read_b128.
// grid (128 y, 8 b), 256 threads
__global__ __launch_bounds__(256) void transpose_kernel(const float* __restrict__ fea,
                                                        u16* __restrict__ feaT) {
    __shared__ float lds_t[64][132];   // row = 528B = 33*16B -> float4-aligned, 2-way banks
    const int y = blockIdx.x;
    const int b = blockIdx.y;
    const int tid = threadIdx.x;

    for (int c0 = 0; c0 < 256; c0 += 64) {
        // load 64 c x 128 x as float4 (16B/lane, coalesced 512B per c-row)
        #pragma unroll
        for (int r = 0; r < 8; ++r) {
            int i  = r * 256 + tid;       // 0..2047
            int c  = i >> 5;              // 0..63
            int x4 = i & 31;              // float4 index
            float4 v = *(const float4*)&fea[(((size_t)(b * 256 + c0 + c)) * 128 + y) * 128 + x4 * 4];
            *(float4*)&lds_t[c][x4 * 4] = v;
        }
        __syncthreads();
        // store: each lane packs 8 consecutive c at fixed x -> one dense 16B store;
        // wave covers 64 consecutive x -> contiguous 1024B per wave.
        #pragma unroll
        for (int jj = 0; jj < 4; ++jj) {
            int p   = jj * 256 + tid;     // 0..1023
            int x   = p & 127;
            int g   = p >> 7;             // 0..7 (granule of 8 c)
            int cb8 = g * 8;
            u32x4 wv;
            #pragma unroll
            for (int k = 0; k < 4; ++k) {
                float f0 = lds_t[cb8 + 2 * k][x];
                float f1 = lds_t[cb8 + 2 * k + 1][x];
                wv[k] = (u32)f2bf(f0) | ((u32)f2bf(f1) << 16);
            }
            int c  = c0 + cb8;
            int ch = c >> 5;
            int cg = (c >> 3) & 3;
            size_t off = (((((size_t)b * 128 + y) * 8 + ch) * 4 + cg) * 128 + x) * 8;
            *(u32x4*)&feaT[off] = wv;
        }
        __syncthreads();
    }
}

// ---------- kernel 3: MFMA conv (shift-GEMM), pipelined ----------
// grid (128 y, 2 co-blocks, 8 b), 256 threads = 4 waves
__global__ __launch_bounds__(256) void conv_mfma(
        const u16* __restrict__ Wmod,   // fragment-ordered, see modulate_kernel
        const u16* __restrict__ feaT,   // [8][128][8][4][128][8] bf16
        float* __restrict__ out) {      // [8][256][128][128]
    // double-buffered fea tile: [buf][row(3)][cg(4)][x(128)][8 ci] bf16 = 2*24 KiB
    __shared__ u16 lds[2][3][4][128][8];
    __shared__ u16 zpad[8];             // 16B zero slot for y/x out-of-range reads

    // bijective XCD swizzle: 2048 wgs = 8 XCDs x 256; each XCD owns one batch b
    // -> its 1.18 MiB Wmod slice stays L2-resident.
    const int lin = blockIdx.x + 128 * (blockIdx.y + 2 * blockIdx.z);
    const int nid = (lin & 7) * 256 + (lin >> 3);
    const int y   = nid & 127;
    const int cbk = (nid >> 7) & 1;
    const int b   = nid >> 8;

    const int tid  = threadIdx.x;
    const int lane = tid & 63;
    const int wave = tid >> 6;
    const int mw = wave & 1;        // co half (64)
    const int nw = wave >> 1;       // pixel half (64)
    const int l4  = lane >> 4;
    const int l15 = lane & 15;

    if (tid < 8) zpad[tid] = 0;

    const bool rok0 = (y > 0);
    const bool rok2 = (y < 127);

    // A-side base (u16 units): per (t,i,ch) add t*65536 + i*4096 + ch*512
    const u16* Abase = Wmod + (size_t)b * 9 * 65536
                            + (size_t)(cbk * 8 + mw * 4) * 4096 + (size_t)lane * 8;

    auto loadA = [&](int t, int i, int ch) -> s8v {
        return *(const s8v*)(Abase + (size_t)t * 65536 + i * 4096 + ch * 512);
    };

    // stage one 32-ci chunk: 24 contiguous 1024B DMA units = r(3) x cg(4) x xq(2)
    auto stage = [&](int buf, int ch) {
        u16* ldsb = &lds[buf][0][0][0][0];
        #pragma unroll
        for (int i = 0; i < 6; ++i) {
            int u  = wave + 4 * i;       // 0..23, wave-uniform
            int r  = u >> 3;
            int cg = (u >> 1) & 3;
            int xq = u & 1;
            int gy = y - 1 + r;
            if ((unsigned)gy < 128u) {
                const u16* g = feaT +
                    (((((size_t)b * 128 + gy) * 8 + ch) * 4 + cg) * 128 + xq * 64) * 8
                    + (size_t)lane * 8;
                async_load16(g, ldsb + ((r * 4 + cg) * 128 + xq * 64) * 8);
            }
        }
    };

    f4v acc[4][4];
    #pragma unroll
    for (int i = 0; i < 4; ++i)
        #pragma unroll
        for (int j = 0; j < 4; ++j) acc[i][j] = (f4v)0.0f;

    s8v afrA[4], afrB[4];

    // prologue: stage chunk 0, preload tap-0 A fragments
    stage(0, 0);
    #pragma unroll
    for (int i = 0; i < 4; ++i) afrA[i] = loadA(0, i, 0);
    __syncthreads();

    const int xb0 = nw * 64 + l15 - 1;

    // chunk body: on entry tap0 frags live in `cur`; on exit next chunk's tap0 in `alt`.
    // Next-chunk DMA issued at t==4: after taps 0-4's afr prefetches (so their vmcnt
    // waits don't force a DMA drain), with taps 5-8 (~2000 cyc) to cover DMA latency.
    auto chunk_body = [&](int ch, s8v (&cur)[4], s8v (&alt)[4]) {
        const u16* bufp = &lds[ch & 1][0][0][0][0];
        #pragma unroll
        for (int t = 0; t < 9; ++t) {
            // prefetch next tap's A fragments (register double-buffer, static indexing)
            if (t < 8) {
                if (t & 1) {
                    #pragma unroll
                    for (int i = 0; i < 4; ++i) cur[i] = loadA(t + 1, i, ch);
                } else {
                    #pragma unroll
                    for (int i = 0; i < 4; ++i) alt[i] = loadA(t + 1, i, ch);
                }
            } else if (ch < 7) {
                #pragma unroll
                for (int i = 0; i < 4; ++i) alt[i] = loadA(0, i, ch + 1);
            }

            const int kh = t / 3, kw = t % 3;
            const bool rok = (kh == 0) ? rok0 : (kh == 2 ? rok2 : true);

            s8v bfr[4];
            #pragma unroll
            for (int j = 0; j < 4; ++j) {
                int x_in = xb0 + j * 16 + kw;     // input x in [-1, 128]
                bool v = rok && ((unsigned)x_in < 128u);
                const u16* bp = v ? (bufp + (((kh * 4 + l4) * 128 + x_in) * 8)) : zpad;
                bfr[j] = *(const s8v*)bp;
            }

            if ((t & 1) == 0) {
                #pragma unroll
                for (int i = 0; i < 4; ++i)
                    #pragma unroll
                    for (int j = 0; j < 4; ++j)
                        acc[i][j] = __builtin_amdgcn_mfma_f32_16x16x32_bf16(
                            cur[i], bfr[j], acc[i][j], 0, 0, 0);
            } else {
                #pragma unroll
                for (int i = 0; i < 4; ++i)
                    #pragma unroll
                    for (int j = 0; j < 4; ++j)
                        acc[i][j] = __builtin_amdgcn_mfma_f32_16x16x32_bf16(
                            alt[i], bfr[j], acc[i][j], 0, 0, 0);
            }

            if (t == 4 && ch < 7) stage((ch + 1) & 1, ch + 1);
        }
    };

    #pragma unroll 1
    for (int m = 0; m < 4; ++m) {
        chunk_body(2 * m, afrA, afrB);
        __syncthreads();
        chunk_body(2 * m + 1, afrB, afrA);
        __syncthreads();
    }

    // epilogue: C/D layout col=lane&15 (pixel), row=quad*4+reg (co)
    const int co_base = cbk * 128 + mw * 64 + l4 * 4;
    const int x_base  = nw * 64 + l15;
    #pragma unroll
    for (int i = 0; i < 4; ++i) {
        #pragma unroll
        for (int reg = 0; reg < 4; ++reg) {
            int co = co_base + i * 16 + reg;
            float* op = out + (((size_t)(b * 256 + co) * 128 + y) * 128 + x_base);
            #pragma unroll
            for (int j = 0; j < 4; ++j) op[j * 16] = acc[i][j][reg];
        }
    }
}

// ---------- launch ----------
extern "C" void kernel_launch(void* const* d_in, const int* in_sizes, int n_in,
                              void* d_out, int out_size, void* d_ws, size_t ws_size,
                              hipStream_t stream) {
    const float* fea       = (const float*)d_in[0];
    const float* norm_feat = (const float*)d_in[1];
    const float* mod_w     = (const float*)d_in[2];
    const float* mod_b     = (const float*)d_in[3];
    const float* weight    = (const float*)d_in[4];
    float* out = (float*)d_out;

    // workspace: Wmod bf16 = 9 MiB, then feaT bf16 = 64 MiB.
    // style (8 KiB fp32) lives at the head of the feaT region (serialized reuse).
    u16* Wmod = (u16*)d_ws;
    u16* feaT = (u16*)((char*)d_ws + 9u * 1024u * 1024u);
    float* style = (float*)feaT;

    style_kernel<<<dim3(8), 256, 0, stream>>>(norm_feat, mod_w, mod_b, style);
    modulate_kernel<<<dim3(256, 8), 256, 0, stream>>>(style, weight, Wmod);
    transpose_kernel<<<dim3(128, 8), 256, 0, stream>>>(fea, feaT);
    conv_mfma<<<dim3(128, 2, 8), 256, 0, stream>>>(Wmod, feaT, out);
}

// Round 2
// 391.190 us; speedup vs baseline: 1.4952x; 1.4526x over previous
//
#include <hip/hip_runtime.h>

typedef unsigned short u16;
typedef unsigned int u32;
typedef short s8v __attribute__((ext_vector_type(8)));    // 8 x bf16 bits (4 VGPRs)
typedef float f16v __attribute__((ext_vector_type(16)));  // 32x32 MFMA accumulator
typedef u32 u32x4 __attribute__((ext_vector_type(4)));

// ---------- helpers ----------
__device__ __forceinline__ u16 f2bf(float f) {
    u32 u = __float_as_uint(f);
    u += 0x7FFFu + ((u >> 16) & 1u);   // round-to-nearest-even
    return (u16)(u >> 16);
}

__device__ __forceinline__ void async_load16(const u16* g, u16* l) {
    // global -> LDS DMA, 16B per lane; LDS dest = wave-uniform base + lane*16
    __builtin_amdgcn_global_load_lds(
        (const __attribute__((address_space(1))) u32*)g,
        (__attribute__((address_space(3))) u32*)l,
        16, 0, 0);
}

// ---------- kernel 0: style (once per b, coalesced mod_w via LDS) ----------
__global__ void style_kernel(const float* __restrict__ norm_feat,  // [8][64]
                             const float* __restrict__ mod_w,      // [256][64]
                             const float* __restrict__ mod_b,      // [256]
                             float* __restrict__ style) {          // [8][256]
    __shared__ float nf[64];
    __shared__ float mw[256][65];
    const int b = blockIdx.x;
    const int tid = threadIdx.x;

    if (tid < 64) nf[tid] = norm_feat[b * 64 + tid];
    #pragma unroll
    for (int i = 0; i < 64; ++i) {
        int idx = i * 256 + tid;
        mw[idx >> 6][idx & 63] = mod_w[idx];
    }
    __syncthreads();

    float s = mod_b[tid];
    #pragma unroll 8
    for (int d = 0; d < 64; ++d) s += nf[d] * mw[tid][d];
    style[b * 256 + tid] = s;
}

// ---------- kernel 1: demod + modulated bf16 weights ----------
// grid (256 co, 8 b), 256 threads (thread = ci)
// Wmod layout for 32x32x16 fragments:
//   [b][t][cob=co>>5 (8)][cib=ci>>4 (16)][lane=(co&31)+32*((ci>>3)&1)][elem=ci&7]
// -> conv's afr load is one fully-coalesced 16B/lane read per (t, i, chunk).
__global__ void modulate_kernel(const float* __restrict__ style,   // [8][256]
                                const float* __restrict__ weight,  // [256][256][9]
                                u16* __restrict__ Wmod) {
    const int co = blockIdx.x;
    const int b  = blockIdx.y;
    const int ci = threadIdx.x;

    __shared__ float red[256];

    const float s = style[b * 256 + ci];

    float w9[9];
    const float* wp = weight + ((size_t)co * 256 + ci) * 9;
    float sq = 0.f;
    #pragma unroll
    for (int t = 0; t < 9; ++t) { w9[t] = wp[t]; sq += w9[t] * w9[t]; }

    red[ci] = sq * s * s;
    __syncthreads();
    for (int off = 128; off > 0; off >>= 1) {
        if (ci < off) red[ci] += red[ci + off];
        __syncthreads();
    }
    const float scale = 1.0f / 48.0f;              // 1/sqrt(256*9)
    const float demod = rsqrtf(scale * scale * red[0] + 1e-8f);
    const float coef  = scale * s * demod;

    // t=0 base; per-t stride = 8*16*64*8 = 65536 u16
    const size_t tile = (((size_t)b * 9 * 8 + (co >> 5)) * 16 + (ci >> 4)) * 512
                      + (size_t)((co & 31) + 32 * ((ci >> 3) & 1)) * 8 + (ci & 7);
    #pragma unroll
    for (int t = 0; t < 9; ++t) {
        Wmod[tile + (size_t)t * 65536] = f2bf(w9[t] * coef);
    }
}

// ---------- kernel 2: NCHW fp32 -> blocked-NHWC bf16 ----------
// feaT layout: [b][y][ch(16)][cg(2)][x(128)][cil(8)] bf16   (c = ch*16 + cg*8 + cil)
// 1024B units (cg, 64 x) contiguous -> conv DMA fully contiguous; linear DMA
// lands as [cg][x][8] in LDS -> dense conflict-free ds_read_b128.
__global__ __launch_bounds__(256) void transpose_kernel(const float* __restrict__ fea,
                                                        u16* __restrict__ feaT) {
    __shared__ float lds_t[64][132];   // row = 528B -> float4-aligned, 2-way banks
    const int y = blockIdx.x;
    const int b = blockIdx.y;
    const int tid = threadIdx.x;

    for (int c0 = 0; c0 < 256; c0 += 64) {
        #pragma unroll
        for (int r = 0; r < 8; ++r) {
            int i  = r * 256 + tid;       // 0..2047
            int c  = i >> 5;              // 0..63
            int x4 = i & 31;              // float4 index
            float4 v = *(const float4*)&fea[(((size_t)(b * 256 + c0 + c)) * 128 + y) * 128 + x4 * 4];
            *(float4*)&lds_t[c][x4 * 4] = v;
        }
        __syncthreads();
        // each lane packs 8 consecutive c at fixed x -> one dense 16B store;
        // a wave covers 64 consecutive x -> contiguous 1024B per wave.
        #pragma unroll
        for (int jj = 0; jj < 4; ++jj) {
            int p   = jj * 256 + tid;     // 0..1023
            int x   = p & 127;
            int g   = p >> 7;             // 0..7 (granule of 8 c)
            int cb8 = g * 8;
            u32x4 wv;
            #pragma unroll
            for (int k = 0; k < 4; ++k) {
                float f0 = lds_t[cb8 + 2 * k][x];
                float f1 = lds_t[cb8 + 2 * k + 1][x];
                wv[k] = (u32)f2bf(f0) | ((u32)f2bf(f1) << 16);
            }
            int c  = c0 + cb8;
            int ch = c >> 4;
            int cg = (c >> 3) & 1;
            size_t off = (((((size_t)b * 128 + y) * 16 + ch) * 2 + cg) * 128 + x) * 8;
            *(u32x4*)&feaT[off] = wv;
        }
        __syncthreads();
    }
}

// ---------- kernel 3: MFMA conv (shift-GEMM), 32x32x16, double-buffered ----------
// grid (128 y, 2 co-blocks, 8 b), 256 threads = 4 waves
__global__ __launch_bounds__(256) void conv_mfma(
        const u16* __restrict__ Wmod,   // fragment-ordered, see modulate_kernel
        const u16* __restrict__ feaT,   // [8][128][16][2][128][8] bf16
        float* __restrict__ out) {      // [8][256][128][128]
    // double-buffered fea tile: [buf][row(3)][cg(2)][x(128)][8 ci] bf16 = 2*12 KiB
    // -> 24.6 KiB total => 6 blocks/CU (24 waves) occupancy cap
    __shared__ u16 lds[2][3][2][128][8];
    __shared__ u16 zpad[8];             // 16B zero slot for out-of-range reads

    // bijective XCD swizzle: 2048 wgs = 8 XCDs x 256; each XCD owns one batch b
    const int lin = blockIdx.x + 128 * (blockIdx.y + 2 * blockIdx.z);
    const int nid = (lin & 7) * 256 + (lin >> 3);
    const int y   = nid & 127;
    const int cbk = (nid >> 7) & 1;
    const int b   = nid >> 8;

    const int tid  = threadIdx.x;
    const int lane = tid & 63;
    const int wave = tid >> 6;
    const int mw  = wave & 1;       // co half (64 of 128)
    const int nw  = wave >> 1;      // pixel half (64)
    const int l31 = lane & 31;
    const int l5  = lane >> 5;      // k-group (8 ci)

    if (tid < 8) zpad[tid] = 0;

    const bool rok0 = (y > 0);
    const bool rok2 = (y < 127);

    // A-side: cob = cbk*4 + mw*2 + i (i=0..1); strides (u16): t=65536, cob=8192, cib=512
    const u16* Abase = Wmod + (size_t)b * 9 * 65536
                            + (size_t)(cbk * 4 + mw * 2) * 8192 + (size_t)lane * 8;

    auto loadA = [&](int t, int i, int ch) -> s8v {
        return *(const s8v*)(Abase + (size_t)t * 65536 + (size_t)i * 8192 + (size_t)ch * 512);
    };

    // stage one 16-ci chunk: 12 contiguous 1024B DMA units = r(3) x cg(2) x xq(2)
    auto stage = [&](int buf, int ch) {
        u16* ldsb = &lds[buf][0][0][0][0];
        #pragma unroll
        for (int i = 0; i < 3; ++i) {
            int u  = wave + 4 * i;       // 0..11, wave-uniform
            int r  = u >> 2;             // 0..2
            int cg = (u >> 1) & 1;
            int xq = u & 1;
            int gy = y - 1 + r;
            if ((unsigned)gy < 128u) {
                const u16* g = feaT +
                    (((((size_t)b * 128 + gy) * 16 + ch) * 2 + cg) * 128 + xq * 64) * 8
                    + (size_t)lane * 8;
                async_load16(g, ldsb + ((r * 2 + cg) * 128 + xq * 64) * 8);
            }
        }
    };

    f16v acc[2][2];
    #pragma unroll
    for (int i = 0; i < 2; ++i)
        #pragma unroll
        for (int j = 0; j < 2; ++j) acc[i][j] = (f16v)0.0f;

    s8v afrA[2], afrB[2];

    // prologue: stage chunk 0, preload tap-0 A fragments
    stage(0, 0);
    #pragma unroll
    for (int i = 0; i < 2; ++i) afrA[i] = loadA(0, i, 0);
    __syncthreads();

    const int xb0 = nw * 64 + l31 - 1;

    // chunk body: tap-0 frags in `cur` on entry; next chunk's tap-0 in `alt` on exit.
    // stage at t==4 (after taps 0-4's afr issues) so afr vmcnt waits force DMA drain
    // no earlier than tap 6 -> ~2 taps + end barrier of cover.
    auto chunk_body = [&](int ch, s8v (&cur)[2], s8v (&alt)[2]) {
        const u16* bufp = &lds[ch & 1][0][0][0][0];
        #pragma unroll
        for (int t = 0; t < 9; ++t) {
            if (t < 8) {
                if (t & 1) {
                    #pragma unroll
                    for (int i = 0; i < 2; ++i) cur[i] = loadA(t + 1, i, ch);
                } else {
                    #pragma unroll
                    for (int i = 0; i < 2; ++i) alt[i] = loadA(t + 1, i, ch);
                }
            } else if (ch < 15) {
                #pragma unroll
                for (int i = 0; i < 2; ++i) alt[i] = loadA(0, i, ch + 1);
            }

            const int kh = t / 3, kw = t % 3;
            const bool rok = (kh == 0) ? rok0 : (kh == 2 ? rok2 : true);

            s8v bfr[2];
            #pragma unroll
            for (int j = 0; j < 2; ++j) {
                int x_in = xb0 + j * 32 + kw;     // input x in [-1, 128]
                bool v = rok && ((unsigned)x_in < 128u);
                const u16* bp = v ? (bufp + (((kh * 2 + l5) * 128 + x_in) * 8)) : zpad;
                bfr[j] = *(const s8v*)bp;
            }

            if ((t & 1) == 0) {
                #pragma unroll
                for (int i = 0; i < 2; ++i)
                    #pragma unroll
                    for (int j = 0; j < 2; ++j)
                        acc[i][j] = __builtin_amdgcn_mfma_f32_32x32x16_bf16(
                            cur[i], bfr[j], acc[i][j], 0, 0, 0);
            } else {
                #pragma unroll
                for (int i = 0; i < 2; ++i)
                    #pragma unroll
                    for (int j = 0; j < 2; ++j)
                        acc[i][j] = __builtin_amdgcn_mfma_f32_32x32x16_bf16(
                            alt[i], bfr[j], acc[i][j], 0, 0, 0);
            }

            if (t == 4 && ch < 15) stage((ch + 1) & 1, ch + 1);
        }
    };

    #pragma unroll 1
    for (int m = 0; m < 8; ++m) {
        chunk_body(2 * m, afrA, afrB);
        __syncthreads();
        chunk_body(2 * m + 1, afrB, afrA);
        __syncthreads();
    }

    // epilogue: C/D layout col(n=pixel)=lane&31, row(m=co)=(reg&3)+8*(reg>>2)+4*(lane>>5)
    const int x_base = nw * 64 + l31;
    #pragma unroll
    for (int i = 0; i < 2; ++i) {
        #pragma unroll
        for (int j = 0; j < 2; ++j) {
            #pragma unroll
            for (int reg = 0; reg < 16; ++reg) {
                int co = cbk * 128 + mw * 64 + i * 32 + (reg & 3) + 8 * (reg >> 2) + 4 * l5;
                out[(((size_t)(b * 256 + co) * 128 + y) * 128) + x_base + j * 32] = acc[i][j][reg];
            }
        }
    }
}

// ---------- launch ----------
extern "C" void kernel_launch(void* const* d_in, const int* in_sizes, int n_in,
                              void* d_out, int out_size, void* d_ws, size_t ws_size,
                              hipStream_t stream) {
    const float* fea       = (const float*)d_in[0];
    const float* norm_feat = (const float*)d_in[1];
    const float* mod_w     = (const float*)d_in[2];
    const float* mod_b     = (const float*)d_in[3];
    const float* weight    = (const float*)d_in[4];
    float* out = (float*)d_out;

    // workspace: Wmod bf16 = 9 MiB, then feaT bf16 = 64 MiB.
    // style (8 KiB fp32) lives at the head of the feaT region (serialized reuse).
    u16* Wmod = (u16*)d_ws;
    u16* feaT = (u16*)((char*)d_ws + 9u * 1024u * 1024u);
    float* style = (float*)feaT;

    style_kernel<<<dim3(8), 256, 0, stream>>>(norm_feat, mod_w, mod_b, style);
    modulate_kernel<<<dim3(256, 8), 256, 0, stream>>>(style, weight, Wmod);
    transpose_kernel<<<dim3(128, 8), 256, 0, stream>>>(fea, feaT);
    conv_mfma<<<dim3(128, 2, 8), 256, 0, stream>>>(Wmod, feaT, out);
}

// Round 3
// 386.202 us; speedup vs baseline: 1.5145x; 1.0129x over previous
//
#include <hip/hip_runtime.h>

typedef unsigned short u16;
typedef unsigned int u32;
typedef short s8v __attribute__((ext_vector_type(8)));    // 8 x bf16 bits (4 VGPRs)
typedef float f16v __attribute__((ext_vector_type(16)));  // 32x32 MFMA accumulator
typedef u32 u32x4 __attribute__((ext_vector_type(4)));

// ---------- helpers ----------
__device__ __forceinline__ u16 f2bf(float f) {
    u32 u = __float_as_uint(f);
    u += 0x7FFFu + ((u >> 16) & 1u);   // round-to-nearest-even
    return (u16)(u >> 16);
}

__device__ __forceinline__ void async_load16(const u16* g, u16* l) {
    // global -> LDS DMA, 16B per lane; LDS dest = wave-uniform base + lane*16
    __builtin_amdgcn_global_load_lds(
        (const __attribute__((address_space(1))) u32*)g,
        (__attribute__((address_space(3))) u32*)l,
        16, 0, 0);
}

// ---------- kernel 0: style (once per b, coalesced mod_w via LDS) ----------
__global__ void style_kernel(const float* __restrict__ norm_feat,  // [8][64]
                             const float* __restrict__ mod_w,      // [256][64]
                             const float* __restrict__ mod_b,      // [256]
                             float* __restrict__ style) {          // [8][256]
    __shared__ float nf[64];
    __shared__ float mw[256][65];
    const int b = blockIdx.x;
    const int tid = threadIdx.x;

    if (tid < 64) nf[tid] = norm_feat[b * 64 + tid];
    #pragma unroll
    for (int i = 0; i < 64; ++i) {
        int idx = i * 256 + tid;
        mw[idx >> 6][idx & 63] = mod_w[idx];
    }
    __syncthreads();

    float s = mod_b[tid];
    #pragma unroll 8
    for (int d = 0; d < 64; ++d) s += nf[d] * mw[tid][d];
    style[b * 256 + tid] = s;
}

// ---------- kernel 1: demod + modulated bf16 weights ----------
// grid (256 co, 8 b), 256 threads (thread = ci)
// Wmod layout for 32x32x16 fragments:
//   [b][t][cob=co>>5 (8)][cib=ci>>4 (16)][lane=(co&31)+32*((ci>>3)&1)][elem=ci&7]
__global__ void modulate_kernel(const float* __restrict__ style,   // [8][256]
                                const float* __restrict__ weight,  // [256][256][9]
                                u16* __restrict__ Wmod) {
    const int co = blockIdx.x;
    const int b  = blockIdx.y;
    const int ci = threadIdx.x;

    __shared__ float red[256];

    const float s = style[b * 256 + ci];

    float w9[9];
    const float* wp = weight + ((size_t)co * 256 + ci) * 9;
    float sq = 0.f;
    #pragma unroll
    for (int t = 0; t < 9; ++t) { w9[t] = wp[t]; sq += w9[t] * w9[t]; }

    red[ci] = sq * s * s;
    __syncthreads();
    for (int off = 128; off > 0; off >>= 1) {
        if (ci < off) red[ci] += red[ci + off];
        __syncthreads();
    }
    const float scale = 1.0f / 48.0f;              // 1/sqrt(256*9)
    const float demod = rsqrtf(scale * scale * red[0] + 1e-8f);
    const float coef  = scale * s * demod;

    // t=0 base; per-t stride = 8*16*64*8 = 65536 u16
    const size_t tile = (((size_t)b * 9 * 8 + (co >> 5)) * 16 + (ci >> 4)) * 512
                      + (size_t)((co & 31) + 32 * ((ci >> 3) & 1)) * 8 + (ci & 7);
    #pragma unroll
    for (int t = 0; t < 9; ++t) {
        Wmod[tile + (size_t)t * 65536] = f2bf(w9[t] * coef);
    }
}

// ---------- kernel 2: NCHW fp32 -> blocked-NHWC bf16 ----------
// feaT layout: [b][y][ch(16)][cg(2)][x(128)][cil(8)] bf16   (c = ch*16 + cg*8 + cil)
__global__ __launch_bounds__(256) void transpose_kernel(const float* __restrict__ fea,
                                                        u16* __restrict__ feaT) {
    __shared__ float lds_t[64][132];   // row = 528B -> float4-aligned, 2-way banks
    const int y = blockIdx.x;
    const int b = blockIdx.y;
    const int tid = threadIdx.x;

    for (int c0 = 0; c0 < 256; c0 += 64) {
        #pragma unroll
        for (int r = 0; r < 8; ++r) {
            int i  = r * 256 + tid;       // 0..2047
            int c  = i >> 5;              // 0..63
            int x4 = i & 31;              // float4 index
            float4 v = *(const float4*)&fea[(((size_t)(b * 256 + c0 + c)) * 128 + y) * 128 + x4 * 4];
            *(float4*)&lds_t[c][x4 * 4] = v;
        }
        __syncthreads();
        #pragma unroll
        for (int jj = 0; jj < 4; ++jj) {
            int p   = jj * 256 + tid;     // 0..1023
            int x   = p & 127;
            int g   = p >> 7;             // 0..7 (granule of 8 c)
            int cb8 = g * 8;
            u32x4 wv;
            #pragma unroll
            for (int k = 0; k < 4; ++k) {
                float f0 = lds_t[cb8 + 2 * k][x];
                float f1 = lds_t[cb8 + 2 * k + 1][x];
                wv[k] = (u32)f2bf(f0) | ((u32)f2bf(f1) << 16);
            }
            int c  = c0 + cb8;
            int ch = c >> 4;
            int cg = (c >> 3) & 1;
            size_t off = (((((size_t)b * 128 + y) * 16 + ch) * 2 + cg) * 128 + x) * 8;
            *(u32x4*)&feaT[off] = wv;
        }
        __syncthreads();
    }
}

// ---------- kernel 3: MFMA conv (shift-GEMM), 32x32x16, 2 y-rows/block ----------
// grid (64 y-pairs, 2 co-blocks, 8 b), 512 threads = 8 waves (mw x nw x yw)
__global__ __launch_bounds__(512, 4) void conv_mfma(
        const u16* __restrict__ Wmod,   // fragment-ordered, see modulate_kernel
        const u16* __restrict__ feaT,   // [8][128][16][2][128][8] bf16
        float* __restrict__ out) {      // [8][256][128][128]
    // double-buffered fea tile: [buf][row(4)][cg(2)][x(128)][8 ci] bf16 = 2*16 KiB
    // row r holds input row (2*yp - 1 + r); OOB rows never read (zpad redirect)
    __shared__ u16 lds[2][4][2][128][8];
    __shared__ u16 zpad[8];             // 16B zero slot for out-of-range reads

    // bijective XCD swizzle: 1024 wgs = 8 XCDs x 128; each XCD owns one batch b
    const int lin = blockIdx.x + 64 * (blockIdx.y + 2 * blockIdx.z);
    const int nid = (lin & 7) * 128 + (lin >> 3);
    const int yp  = nid & 63;           // y-pair: rows 2*yp, 2*yp+1
    const int cbk = (nid >> 6) & 1;
    const int b   = nid >> 7;

    const int tid  = threadIdx.x;
    const int lane = tid & 63;
    const int wave = tid >> 6;          // 0..7
    const int mw  = wave & 1;           // co half (64 of 128)
    const int nw  = (wave >> 1) & 1;    // pixel half (64)
    const int yw  = wave >> 2;          // output row within pair
    const int l31 = lane & 31;
    const int l5  = lane >> 5;          // k-group (8 ci)

    if (tid < 8) zpad[tid] = 0;

    const int y_out = 2 * yp + yw;
    // validity of input row y_out-1+kh
    const bool rokv[3] = { (y_out > 0), true, (y_out < 127) };

    // A-side: cob = cbk*4 + mw*2 + i; strides (u16): t=65536, cob=8192, cib=512
    const u16* Abase = Wmod + (size_t)b * 9 * 65536
                            + (size_t)(cbk * 4 + mw * 2) * 8192 + (size_t)lane * 8;

    auto loadA = [&](int t, int i, int ch) -> s8v {
        return *(const s8v*)(Abase + (size_t)t * 65536 + (size_t)i * 8192 + (size_t)ch * 512);
    };

    // stage one 16-ci chunk: 16 contiguous 1024B DMA units = r(4) x cg(2) x xq(2)
    auto stage = [&](int buf, int ch) {
        u16* ldsb = &lds[buf][0][0][0][0];
        #pragma unroll
        for (int i = 0; i < 2; ++i) {
            int u  = wave + 8 * i;       // 0..15, wave-uniform
            int r  = u >> 2;             // 0..3
            int cg = (u >> 1) & 1;
            int xq = u & 1;
            int gy = 2 * yp - 1 + r;
            if ((unsigned)gy < 128u) {
                const u16* g = feaT +
                    (((((size_t)b * 128 + gy) * 16 + ch) * 2 + cg) * 128 + xq * 64) * 8
                    + (size_t)lane * 8;
                async_load16(g, ldsb + ((r * 2 + cg) * 128 + xq * 64) * 8);
            }
        }
    };

    f16v acc[2][2];
    #pragma unroll
    for (int i = 0; i < 2; ++i)
        #pragma unroll
        for (int j = 0; j < 2; ++j) acc[i][j] = (f16v)0.0f;

    // A-fragment ring: distance-3 prefetch, 9 taps % 3 == 0 -> static ring index
    s8v fr[3][2];

    // prologue: stage chunk 0, preload taps 0..2 of chunk 0
    stage(0, 0);
    #pragma unroll
    for (int g = 0; g < 3; ++g) {
        fr[g][0] = loadA(g, 0, 0);
        fr[g][1] = loadA(g, 1, 0);
    }
    __syncthreads();

    const int xb0 = nw * 64 + l31 - 1;

    #pragma unroll 1
    for (int ch = 0; ch < 16; ++ch) {
        const u16* bufp = &lds[ch & 1][0][0][0][0];
        #pragma unroll
        for (int t = 0; t < 9; ++t) {
            const int kh = t / 3, kw = t % 3;
            const int rr = kh + yw;          // LDS row for this tap
            const bool rok = rokv[kh];

            s8v bfr[2];
            #pragma unroll
            for (int j = 0; j < 2; ++j) {
                int x_in = xb0 + j * 32 + kw;     // input x in [-1, 128]
                bool v = rok && ((unsigned)x_in < 128u);
                const u16* bp = v ? (bufp + (((rr * 2 + l5) * 128 + x_in) * 8)) : zpad;
                bfr[j] = *(const s8v*)bp;
            }

            #pragma unroll
            for (int i = 0; i < 2; ++i)
                #pragma unroll
                for (int j = 0; j < 2; ++j)
                    acc[i][j] = __builtin_amdgcn_mfma_f32_32x32x16_bf16(
                        fr[t % 3][i], bfr[j], acc[i][j], 0, 0, 0);

            // refill ring slot (t%3) with the fragment needed 3 taps ahead;
            // issued after the MFMAs so the consume-wait above never has to
            // drain the fea DMA (per-wave DMA = 2 entries, drained only at the
            // chunk-end barrier ~5 taps after issue).
            if (t < 6) {
                fr[t % 3][0] = loadA(t + 3, 0, ch);
                fr[t % 3][1] = loadA(t + 3, 1, ch);
            } else if (ch < 15) {
                fr[t % 3][0] = loadA(t - 6, 0, ch + 1);
                fr[t % 3][1] = loadA(t - 6, 1, ch + 1);
            }

            if (t == 3 && ch < 15) stage((ch + 1) & 1, ch + 1);
        }
        __syncthreads();
    }

    // epilogue: C/D layout col(n=pixel)=lane&31, row(m=co)=(reg&3)+8*(reg>>2)+4*(lane>>5)
    const int x_base = nw * 64 + l31;
    #pragma unroll
    for (int i = 0; i < 2; ++i) {
        #pragma unroll
        for (int j = 0; j < 2; ++j) {
            #pragma unroll
            for (int reg = 0; reg < 16; ++reg) {
                int co = cbk * 128 + mw * 64 + i * 32 + (reg & 3) + 8 * (reg >> 2) + 4 * l5;
                out[(((size_t)(b * 256 + co) * 128 + y_out) * 128) + x_base + j * 32] = acc[i][j][reg];
            }
        }
    }
}

// ---------- launch ----------
extern "C" void kernel_launch(void* const* d_in, const int* in_sizes, int n_in,
                              void* d_out, int out_size, void* d_ws, size_t ws_size,
                              hipStream_t stream) {
    const float* fea       = (const float*)d_in[0];
    const float* norm_feat = (const float*)d_in[1];
    const float* mod_w     = (const float*)d_in[2];
    const float* mod_b     = (const float*)d_in[3];
    const float* weight    = (const float*)d_in[4];
    float* out = (float*)d_out;

    // workspace: Wmod bf16 = 9 MiB, then feaT bf16 = 64 MiB.
    // style (8 KiB fp32) lives at the head of the feaT region (serialized reuse).
    u16* Wmod = (u16*)d_ws;
    u16* feaT = (u16*)((char*)d_ws + 9u * 1024u * 1024u);
    float* style = (float*)feaT;

    style_kernel<<<dim3(8), 256, 0, stream>>>(norm_feat, mod_w, mod_b, style);
    modulate_kernel<<<dim3(256, 8), 256, 0, stream>>>(style, weight, Wmod);
    transpose_kernel<<<dim3(128, 8), 256, 0, stream>>>(fea, feaT);
    conv_mfma<<<dim3(64, 2, 8), 512, 0, stream>>>(Wmod, feaT, out);
}

// Round 4
// 378.922 us; speedup vs baseline: 1.5436x; 1.0192x over previous
//
#include <hip/hip_runtime.h>

typedef unsigned short u16;
typedef unsigned int u32;
typedef short s8v __attribute__((ext_vector_type(8)));    // 8 x bf16 bits (4 VGPRs)
typedef float f16v __attribute__((ext_vector_type(16)));  // 32x32 MFMA accumulator
typedef u32 u32x4 __attribute__((ext_vector_type(4)));

// ---------- helpers ----------
__device__ __forceinline__ u16 f2bf(float f) {
    u32 u = __float_as_uint(f);
    u += 0x7FFFu + ((u >> 16) & 1u);   // round-to-nearest-even
    return (u16)(u >> 16);
}

__device__ __forceinline__ void async_load16(const u16* g, u16* l) {
    // global -> LDS DMA, 16B per lane; LDS dest = wave-uniform base + lane*16
    __builtin_amdgcn_global_load_lds(
        (const __attribute__((address_space(1))) u32*)g,
        (__attribute__((address_space(3))) u32*)l,
        16, 0, 0);
}

// ---------- kernel 0: style (once per b, coalesced mod_w via LDS) ----------
__global__ void style_kernel(const float* __restrict__ norm_feat,  // [8][64]
                             const float* __restrict__ mod_w,      // [256][64]
                             const float* __restrict__ mod_b,      // [256]
                             float* __restrict__ style) {          // [8][256]
    __shared__ float nf[64];
    __shared__ float mw[256][65];
    const int b = blockIdx.x;
    const int tid = threadIdx.x;

    if (tid < 64) nf[tid] = norm_feat[b * 64 + tid];
    #pragma unroll
    for (int i = 0; i < 64; ++i) {
        int idx = i * 256 + tid;
        mw[idx >> 6][idx & 63] = mod_w[idx];
    }
    __syncthreads();

    float s = mod_b[tid];
    #pragma unroll 8
    for (int d = 0; d < 64; ++d) s += nf[d] * mw[tid][d];
    style[b * 256 + tid] = s;
}

// ---------- kernel 1: demod + modulated bf16 weights ----------
// grid (256 co, 8 b), 256 threads (thread = ci)
// Wmod layout for 32x32x16 fragments:
//   [b][t][cob=co>>5 (8)][cib=ci>>4 (16)][lane=(co&31)+32*((ci>>3)&1)][elem=ci&7]
__global__ void modulate_kernel(const float* __restrict__ style,   // [8][256]
                                const float* __restrict__ weight,  // [256][256][9]
                                u16* __restrict__ Wmod) {
    const int co = blockIdx.x;
    const int b  = blockIdx.y;
    const int ci = threadIdx.x;

    __shared__ float red[256];

    const float s = style[b * 256 + ci];

    float w9[9];
    const float* wp = weight + ((size_t)co * 256 + ci) * 9;
    float sq = 0.f;
    #pragma unroll
    for (int t = 0; t < 9; ++t) { w9[t] = wp[t]; sq += w9[t] * w9[t]; }

    red[ci] = sq * s * s;
    __syncthreads();
    for (int off = 128; off > 0; off >>= 1) {
        if (ci < off) red[ci] += red[ci + off];
        __syncthreads();
    }
    const float scale = 1.0f / 48.0f;              // 1/sqrt(256*9)
    const float demod = rsqrtf(scale * scale * red[0] + 1e-8f);
    const float coef  = scale * s * demod;

    // t=0 base; per-t stride = 8*16*64*8 = 65536 u16
    const size_t tile = (((size_t)b * 9 * 8 + (co >> 5)) * 16 + (ci >> 4)) * 512
                      + (size_t)((co & 31) + 32 * ((ci >> 3) & 1)) * 8 + (ci & 7);
    #pragma unroll
    for (int t = 0; t < 9; ++t) {
        Wmod[tile + (size_t)t * 65536] = f2bf(w9[t] * coef);
    }
}

// ---------- kernel 2: NCHW fp32 -> blocked-NHWC bf16 ----------
// feaT layout: [b][y][ch(16)][cg(2)][x(128)][cil(8)] bf16   (c = ch*16 + cg*8 + cil)
__global__ __launch_bounds__(256) void transpose_kernel(const float* __restrict__ fea,
                                                        u16* __restrict__ feaT) {
    __shared__ float lds_t[64][132];   // row = 528B -> float4-aligned, 2-way banks
    const int y = blockIdx.x;
    const int b = blockIdx.y;
    const int tid = threadIdx.x;

    for (int c0 = 0; c0 < 256; c0 += 64) {
        #pragma unroll
        for (int r = 0; r < 8; ++r) {
            int i  = r * 256 + tid;       // 0..2047
            int c  = i >> 5;              // 0..63
            int x4 = i & 31;              // float4 index
            float4 v = *(const float4*)&fea[(((size_t)(b * 256 + c0 + c)) * 128 + y) * 128 + x4 * 4];
            *(float4*)&lds_t[c][x4 * 4] = v;
        }
        __syncthreads();
        #pragma unroll
        for (int jj = 0; jj < 4; ++jj) {
            int p   = jj * 256 + tid;     // 0..1023
            int x   = p & 127;
            int g   = p >> 7;             // 0..7 (granule of 8 c)
            int cb8 = g * 8;
            u32x4 wv;
            #pragma unroll
            for (int k = 0; k < 4; ++k) {
                float f0 = lds_t[cb8 + 2 * k][x];
                float f1 = lds_t[cb8 + 2 * k + 1][x];
                wv[k] = (u32)f2bf(f0) | ((u32)f2bf(f1) << 16);
            }
            int c  = c0 + cb8;
            int ch = c >> 4;
            int cg = (c >> 3) & 1;
            size_t off = (((((size_t)b * 128 + y) * 16 + ch) * 2 + cg) * 128 + x) * 8;
            *(u32x4*)&feaT[off] = wv;
        }
        __syncthreads();
    }
}

// ---------- kernel 3: MFMA conv (shift-GEMM), 32x32x16, counted-vmcnt pipeline ----
// grid (64 y-pairs, 2 co-blocks, 8 b), 512 threads = 8 waves (mw x nw x yw)
__global__ __launch_bounds__(512, 4) void conv_mfma(
        const u16* __restrict__ Wmod,   // fragment-ordered, see modulate_kernel
        const u16* __restrict__ feaT,   // [8][128][16][2][128][8] bf16
        float* __restrict__ out) {      // [8][256][128][128]
    // per-parity: 8192 u16 fea data ([row4][cg2][x128][8ci]) + 24 u16 zero pad
    // (pad absorbs zpad-redirected reads at any tap immediate <= +16 u16 + 8 read)
    __shared__ u16 lds[2][8216];        // 32,864 B total

    // bijective XCD swizzle: 1024 wgs = 8 XCDs x 128; each XCD owns one batch b
    const int lin = blockIdx.x + 64 * (blockIdx.y + 2 * blockIdx.z);
    const int nid = (lin & 7) * 128 + (lin >> 3);
    const int yp  = nid & 63;           // y-pair: rows 2*yp, 2*yp+1
    const int cbk = (nid >> 6) & 1;
    const int b   = nid >> 7;

    const int tid  = threadIdx.x;
    const int lane = tid & 63;
    const int wave = tid >> 6;          // 0..7
    const int mw  = wave & 1;           // co half (64 of 128)
    const int nw  = (wave >> 1) & 1;    // pixel half (64)
    const int yw  = wave >> 2;          // output row within pair
    const int l31 = lane & 31;
    const int l5  = lane >> 5;          // k-group (8 ci)

    // zero both parity pads (24 u16 each)
    if (tid < 24) { lds[0][8192 + tid] = 0; lds[1][8192 + tid] = 0; }

    const int y_out = 2 * yp + yw;

    // ---- precompute all B-side LDS offsets (u16 units, rel. to parity base) ----
    // tap (kh,kw), j: addr = base[kh][j] + kw*8   (kw folded into ds_read imm)
    // boundary combos (kw=0,j=0) and (kw=2,j=1) pre-resolved per lane; y-edge
    // validity folded in (whole row -> zero pad at 8192).
    const int xb0 = nw * 64 + l31 - 1;
    int ofj0[3], ofj1[3], bq0[3], bq2[3];
    #pragma unroll
    for (int kh = 0; kh < 3; ++kh) {
        const int rr = kh + yw;
        const int rowb = ((rr * 2 + l5) * 128) * 8;
        const bool rok = (kh == 0) ? (y_out > 0) : (kh == 2 ? (y_out < 127) : true);
        const int o0 = rowb + xb0 * 8;      // j=0 base at kw=0 (lane-edge: never deref'd at imm 0)
        const int o1 = o0 + 256;            // j=1 base at kw=0
        ofj0[kh] = rok ? o0 : 8192;
        ofj1[kh] = rok ? o1 : 8192;
        bq0[kh]  = (rok && xb0 >= 0)       ? o0        : 8192;   // (kw=0,j=0)
        bq2[kh]  = (rok && xb0 + 34 < 128) ? (o1 + 16) : 8192;   // (kw=2,j=1), +16 = kw*8
    }

    // A-side: cob = cbk*4 + mw*2 + i; strides (u16): t=65536, cob=8192, cib=512
    const u16* Abase = Wmod + (size_t)b * 9 * 65536
                            + (size_t)(cbk * 4 + mw * 2) * 8192 + (size_t)lane * 8;

    auto loadA = [&](int t, int i, int ch) -> s8v {
        return *(const s8v*)(Abase + (size_t)t * 65536 + (size_t)i * 8192 + (size_t)ch * 512);
    };

    // stage one 16-ci chunk: 16 contiguous 1024B DMA units = r(4) x cg(2) x xq(2)
    auto stage = [&](int buf, int ch) {
        u16* ldsb = &lds[buf][0];
        #pragma unroll
        for (int i = 0; i < 2; ++i) {
            int u  = wave + 8 * i;       // 0..15, wave-uniform
            int r  = u >> 2;             // 0..3
            int cg = (u >> 1) & 1;
            int xq = u & 1;
            int gy = 2 * yp - 1 + r;
            if ((unsigned)gy < 128u) {
                const u16* g = feaT +
                    (((((size_t)b * 128 + gy) * 16 + ch) * 2 + cg) * 128 + xq * 64) * 8
                    + (size_t)lane * 8;
                async_load16(g, ldsb + ((r * 2 + cg) * 128 + xq * 64) * 8);
            }
        }
    };

    f16v acc[2][2];
    #pragma unroll
    for (int i = 0; i < 2; ++i)
        #pragma unroll
        for (int j = 0; j < 2; ++j) acc[i][j] = (f16v)0.0f;

    // A-fragment ring: distance-3 prefetch, 9 taps % 3 == 0 -> static ring index
    s8v fr[3][2];

    // prologue: stage chunk 0, preload taps 0..2 of chunk 0 (full drain once, OK)
    stage(0, 0);
    #pragma unroll
    for (int g = 0; g < 3; ++g) {
        fr[g][0] = loadA(g, 0, 0);
        fr[g][1] = loadA(g, 1, 0);
    }
    __syncthreads();

    #pragma unroll 1
    for (int ch = 0; ch < 16; ++ch) {
        const u16* basep = &lds[ch & 1][0];
        #pragma unroll
        for (int t = 0; t < 9; ++t) {
            const int kh = t / 3, kw = t % 3;

            s8v bfr[2];
            {
                const u16* a0 = (kw == 0) ? (basep + bq0[kh]) : (basep + ofj0[kh] + kw * 8);
                const u16* a1 = (kw == 2) ? (basep + bq2[kh]) : (basep + ofj1[kh] + kw * 8);
                bfr[0] = *(const s8v*)a0;
                bfr[1] = *(const s8v*)a1;
            }

            __builtin_amdgcn_s_setprio(1);
            #pragma unroll
            for (int i = 0; i < 2; ++i)
                #pragma unroll
                for (int j = 0; j < 2; ++j)
                    acc[i][j] = __builtin_amdgcn_mfma_f32_32x32x16_bf16(
                        fr[t % 3][i], bfr[j], acc[i][j], 0, 0, 0);
            __builtin_amdgcn_s_setprio(0);

            // refill ring slot (t%3) with the fragment needed 3 taps ahead.
            // FIFO: t4/t5 refills are consumed at t7/t8 -> their waits drain the
            // t3 stage DMAs; only taps 6-8 refills (6 entries) live at chunk end.
            if (t < 6) {
                fr[t % 3][0] = loadA(t + 3, 0, ch);
                fr[t % 3][1] = loadA(t + 3, 1, ch);
            } else if (ch < 15) {
                fr[t % 3][0] = loadA(t - 6, 0, ch + 1);
                fr[t % 3][1] = loadA(t - 6, 1, ch + 1);
            }

            if (t == 3 && ch < 15) {
                // pin the DMA's position in the vmem FIFO (vmcnt(6) proof relies on it)
                __builtin_amdgcn_sched_barrier(0);
                stage((ch + 1) & 1, ch + 1);
                __builtin_amdgcn_sched_barrier(0);
            }
        }

        if (ch < 15) {
            // counted-vmcnt barrier (T4): keep the 6 next-chunk A-refills in
            // flight across the barrier; everything older (incl. the stage
            // DMAs) is forced complete. No full drain in the main loop.
            asm volatile("s_waitcnt vmcnt(6)" ::: "memory");
            __builtin_amdgcn_sched_barrier(0);
            __builtin_amdgcn_s_barrier();
            __builtin_amdgcn_sched_barrier(0);
        }
    }

    // epilogue: C/D layout col(n=pixel)=lane&31, row(m=co)=(reg&3)+8*(reg>>2)+4*(lane>>5)
    const int x_base = nw * 64 + l31;
    #pragma unroll
    for (int i = 0; i < 2; ++i) {
        #pragma unroll
        for (int j = 0; j < 2; ++j) {
            #pragma unroll
            for (int reg = 0; reg < 16; ++reg) {
                int co = cbk * 128 + mw * 64 + i * 32 + (reg & 3) + 8 * (reg >> 2) + 4 * l5;
                out[(((size_t)(b * 256 + co) * 128 + y_out) * 128) + x_base + j * 32] = acc[i][j][reg];
            }
        }
    }
}

// ---------- launch ----------
extern "C" void kernel_launch(void* const* d_in, const int* in_sizes, int n_in,
                              void* d_out, int out_size, void* d_ws, size_t ws_size,
                              hipStream_t stream) {
    const float* fea       = (const float*)d_in[0];
    const float* norm_feat = (const float*)d_in[1];
    const float* mod_w     = (const float*)d_in[2];
    const float* mod_b     = (const float*)d_in[3];
    const float* weight    = (const float*)d_in[4];
    float* out = (float*)d_out;

    // workspace: Wmod bf16 = 9 MiB, then feaT bf16 = 64 MiB.
    // style (8 KiB fp32) lives at the head of the feaT region (serialized reuse).
    u16* Wmod = (u16*)d_ws;
    u16* feaT = (u16*)((char*)d_ws + 9u * 1024u * 1024u);
    float* style = (float*)feaT;

    style_kernel<<<dim3(8), 256, 0, stream>>>(norm_feat, mod_w, mod_b, style);
    modulate_kernel<<<dim3(256, 8), 256, 0, stream>>>(style, weight, Wmod);
    transpose_kernel<<<dim3(128, 8), 256, 0, stream>>>(fea, feaT);
    conv_mfma<<<dim3(64, 2, 8), 512, 0, stream>>>(Wmod, feaT, out);
}